// Round 9
// baseline (147.214 us; speedup 1.0000x reference)
//
#include <hip/hip_runtime.h>
#include <cstdint>
#include <cstddef>

// B=1, L=2048, DIM=512, H=8, D=64, STEPS=1024.  R9: 4-kernel all-MFMA pipeline.
// R9 change (single variable): k_qs_ln __launch_bounds__(512, 2).
//   R8 profile showed VGPR_Count=52 with acc[8]+y[8][4]+a/p[8][4] live ->
//   compiler targeted 8 waves/SIMD (<=64 VGPR) and SPILLED everything to
//   scratch; kernel sat 95% idle on scratch latency (45us, VALUBusy 4.5%).
//   (512,2) = 2 waves/EU = exactly 1 block/CU -> VGPR cap ~256, no spills.
// Timing model: measured dur includes ~86us of harness ws-repoison fills;
// addressable kernel+gap pool at R8 is ~60us, k_qs_ln was ~45 of it.
//
//  pipeline: k_prep -> k_qs_ln -> k_flash6 -> k_gemm(out)

typedef __attribute__((ext_vector_type(8))) short short8;
typedef __attribute__((ext_vector_type(4))) float f32x4;

#define MFMA16(a, b, c) __builtin_amdgcn_mfma_f32_16x16x32_bf16((a), (b), (c), 0, 0, 0)

static constexpr size_t B_ATTB = 0;                        // bf16 [2048][512] = 2 MB
static constexpr size_t B_UB   = (size_t)2 * 1024 * 1024;  // bf16 [8][2048][128] = 4 MB
static constexpr size_t B_WB   = B_UB + (size_t)4 * 1024 * 1024;
static constexpr size_t B_VT   = B_WB + (size_t)4 * 1024 * 1024;   // bf16 [8][64][2048]
static constexpr size_t B_WQT  = B_VT + (size_t)2 * 1024 * 1024;   // frag-packed, 1 MB
static constexpr size_t B_WOT  = B_WQT + (size_t)1 * 1024 * 1024;  // bf16 [512][512]

__device__ __forceinline__ unsigned short f2bf(float f) {
  unsigned u = __float_as_uint(f);
  return (unsigned short)((u + 0x7FFFu + ((u >> 16) & 1u)) >> 16);
}

// ---------------- prep: x -> vT;  Wq -> WqTp (frag-packed);  Wo -> WoT ----------
__global__ __launch_bounds__(256) void k_prep(const float* __restrict__ x,
    const float* __restrict__ Wq, const float* __restrict__ Wo,
    unsigned short* __restrict__ vT, unsigned short* __restrict__ WqTp,
    unsigned short* __restrict__ WoT) {
  __shared__ float tl[64 * 65];
  const int t = threadIdx.x, b = blockIdx.x;
  if (b < 256) {
    const int i0 = (b >> 3) * 64, h = b & 7;
    #pragma unroll
    for (int it = 0; it < 16; ++it) {
      int n = t + 256 * it;
      int r = n >> 6, c = n & 63;
      tl[r * 65 + c] = x[(size_t)(i0 + r) * 512 + h * 64 + c];
    }
    __syncthreads();
    #pragma unroll
    for (int it = 0; it < 16; ++it) {
      int n = t + 256 * it;
      int d = n >> 6, ii = n & 63;
      vT[(size_t)(h * 64 + d) * 2048 + i0 + ii] = f2bf(tl[ii * 65 + d]);
    }
  } else if (b < 384) {
    const int bb = b - 256;
    const int k0 = (bb >> 4) * 64, n0 = (bb & 15) * 64;
    #pragma unroll
    for (int it = 0; it < 16; ++it) {
      int n = t + 256 * it;
      int r = n >> 6, c = n & 63;
      tl[r * 65 + c] = Wq[(size_t)(k0 + r) * 1024 + n0 + c];
    }
    __syncthreads();
    #pragma unroll
    for (int it = 0; it < 16; ++it) {
      int n = t + 256 * it;
      int rr = n >> 6, cc = n & 63;       // rr = n-local, cc = k-local
      int nn = n0 + rr, kk = k0 + cc;
      int nt = nn >> 4, mm = nn & 15;
      int kc32 = kk >> 5, qd = (kk >> 3) & 3, j = kk & 7;
      WqTp[(((size_t)nt * 16 + kc32) * 64 + qd * 16 + mm) * 8 + j] =
          f2bf(tl[cc * 65 + rr]);
    }
  } else {
    const int bb = b - 384;
    const int k0 = (bb >> 3) * 64, n0 = (bb & 7) * 64;
    #pragma unroll
    for (int it = 0; it < 16; ++it) {
      int n = t + 256 * it;
      int r = n >> 6, c = n & 63;
      tl[r * 65 + c] = Wo[(size_t)(k0 + r) * 512 + n0 + c];
    }
    __syncthreads();
    #pragma unroll
    for (int it = 0; it < 16; ++it) {
      int n = t + 256 * it;
      int rr = n >> 6, cc = n & 63;
      WoT[(size_t)(n0 + rr) * 512 + k0 + cc] = f2bf(tl[cc * 65 + rr]);
    }
  }
}

// -------- fused qs-GEMM + LN + activations + cos/sin features ----------------
// (512, 2): 2 waves/EU = 1 block/CU, VGPR cap ~256 -> no scratch spills.
__global__ __launch_bounds__(512, 2) void k_qs_ln(const float* __restrict__ x,
    const unsigned short* __restrict__ WqTp, const float* __restrict__ bq,
    const float* __restrict__ lnw, const float* __restrict__ lnb,
    const float* __restrict__ fr, const float* __restrict__ psh,
    unsigned short* __restrict__ Ub, unsigned short* __restrict__ Wb) {
  __shared__ __align__(16) unsigned short s_a[16 * 520];  // A rows, stride 520 bf16
  __shared__ float s_amp[16 * 516];                       // normalized amp [row][col]
  __shared__ float red[8 * 16 * 2];                       // rowstats [wave][row][{s,s2}]
  __shared__ float red2[4 * 16];                          // amp-norm [ampwave][row]
  const int r0 = blockIdx.x * 16, t = threadIdx.x;
  const int w = t >> 6, lane = t & 63, m = lane & 15, quad = lane >> 4;
  {
    const int row = t >> 5, cs = (t & 31) * 16;
    const float4* xr = (const float4*)(x + (size_t)(r0 + row) * 512 + cs);
    unsigned short tmp[16];
    #pragma unroll
    for (int q4 = 0; q4 < 4; ++q4) {
      float4 v = xr[q4];
      tmp[q4 * 4 + 0] = f2bf(v.x); tmp[q4 * 4 + 1] = f2bf(v.y);
      tmp[q4 * 4 + 2] = f2bf(v.z); tmp[q4 * 4 + 3] = f2bf(v.w);
    }
    *(short8*)(s_a + row * 520 + cs)     = *(short8*)(tmp);
    *(short8*)(s_a + row * 520 + cs + 8) = *(short8*)(tmp + 8);
  }
  __syncthreads();
  f32x4 acc[8] = {{0,0,0,0},{0,0,0,0},{0,0,0,0},{0,0,0,0},
                  {0,0,0,0},{0,0,0,0},{0,0,0,0},{0,0,0,0}};
  for (int kc32 = 0; kc32 < 16; ++kc32) {
    short8 af = *(const short8*)(s_a + m * 520 + kc32 * 32 + quad * 8);
    const unsigned short* bp =
        WqTp + (((size_t)(w * 8) * 16 + kc32) * 64 + lane) * 8;
    #pragma unroll
    for (int nt = 0; nt < 8; ++nt) {
      short8 bf = *(const short8*)(bp + (size_t)nt * 8192);
      acc[nt] = MFMA16(af, bf, acc[nt]);
    }
  }
  #pragma unroll
  for (int nt = 0; nt < 8; ++nt) {
    float bv = bq[w * 128 + nt * 16 + m];
    #pragma unroll
    for (int r = 0; r < 4; ++r) acc[nt][r] += bv;
  }
  float s1[4] = {0, 0, 0, 0}, s2[4] = {0, 0, 0, 0};
  #pragma unroll
  for (int r = 0; r < 4; ++r)
    #pragma unroll
    for (int nt = 0; nt < 8; ++nt) {
      float v = acc[nt][r];
      s1[r] += v; s2[r] += v * v;
    }
  #pragma unroll
  for (int off = 1; off < 16; off <<= 1)
    #pragma unroll
    for (int r = 0; r < 4; ++r) {
      s1[r] += __shfl_xor(s1[r], off, 64);
      s2[r] += __shfl_xor(s2[r], off, 64);
    }
  if (m == 0)
    #pragma unroll
    for (int r = 0; r < 4; ++r) {
      red[(w * 16 + quad * 4 + r) * 2]     = s1[r];
      red[(w * 16 + quad * 4 + r) * 2 + 1] = s2[r];
    }
  __syncthreads();
  float mu[4], rstd[4];
  #pragma unroll
  for (int r = 0; r < 4; ++r) {
    int row = quad * 4 + r;
    float S = 0, S2 = 0;
    #pragma unroll
    for (int wp = 0; wp < 8; ++wp) {
      S  += red[(wp * 16 + row) * 2];
      S2 += red[(wp * 16 + row) * 2 + 1];
    }
    mu[r] = S * (1.0f / 1024.0f);
    float var = S2 * (1.0f / 1024.0f) - mu[r] * mu[r];
    rstd[r] = 1.0f / sqrtf(var + 1e-5f);
  }
  float y[8][4];
  #pragma unroll
  for (int nt = 0; nt < 8; ++nt) {
    int c = w * 128 + nt * 16 + m;
    float gw = lnw[c], gb = lnb[c];
    #pragma unroll
    for (int r = 0; r < 4; ++r)
      y[nt][r] = (acc[nt][r] - mu[r]) * rstd[r] * gw + gb;
  }
  const float PI_F = 3.14159265358979323846f;
  if (w < 4) {
    float a[8][4];
    float na[4] = {0, 0, 0, 0};
    #pragma unroll
    for (int nt = 0; nt < 8; ++nt)
      #pragma unroll
      for (int r = 0; r < 4; ++r) {
        float v = __builtin_amdgcn_rcpf(1.0f + __expf(-y[nt][r]));
        a[nt][r] = v;
        na[r] += v * v;
      }
    #pragma unroll
    for (int off = 1; off < 16; off <<= 1)
      #pragma unroll
      for (int r = 0; r < 4; ++r) na[r] += __shfl_xor(na[r], off, 64);
    if (m == 0)
      #pragma unroll
      for (int r = 0; r < 4; ++r) red2[w * 16 + quad * 4 + r] = na[r];
    __syncthreads();   // #3: red2 ready
    float inv[4];
    #pragma unroll
    for (int r = 0; r < 4; ++r) {
      int row = quad * 4 + r;
      float N = red2[row] + red2[16 + row] + red2[32 + row] + red2[48 + row];
      inv[r] = 1.0f / (sqrtf(N) + 1e-8f);
    }
    #pragma unroll
    for (int nt = 0; nt < 8; ++nt)
      #pragma unroll
      for (int r = 0; r < 4; ++r)
        s_amp[(quad * 4 + r) * 516 + w * 128 + nt * 16 + m] = a[nt][r] * inv[r];
    __syncthreads();   // #4: s_amp ready
  } else {
    float p[8][4];
    #pragma unroll
    for (int nt = 0; nt < 8; ++nt)
      #pragma unroll
      for (int r = 0; r < 4; ++r) {
        float e2 = __expf(2.0f * y[nt][r]);
        p[nt][r] = (1.0f - 2.0f * __builtin_amdgcn_rcpf(e2 + 1.0f)) * PI_F;
      }
    __syncthreads();   // #3 (match amp waves)
    __syncthreads();   // #4: s_amp ready
    const double GAM = 1024.0 / 1023.0;   // table-step rescale (linspace endpoint)
    const int hbase = (w - 4) * 2;
    float c1[2], s1g[2];
    #pragma unroll
    for (int hh = 0; hh < 2; ++hh) {
      c1[hh]  = (float)((double)fr[hbase + hh] * GAM);
      s1g[hh] = (float)((double)psh[hbase + hh] * GAM);
    }
    #pragma unroll
    for (int nt = 0; nt < 8; ++nt) {
      const int hh = nt >> 2;
      const int pc = (w - 4) * 128 + nt * 16 + m;
      const int d = pc & 63;
      #pragma unroll
      for (int r = 0; r < 4; ++r) {
        const int i = r0 + quad * 4 + r;
        float af = s_amp[(quad * 4 + r) * 516 + pc];
        float A = fmaf(p[nt][r], c1[hh], s1g[hh]);
        float Bp = p[nt][r] * c1[hh];
        float cA, sA, cB, sB;
        __sincosf(A, &sA, &cA);
        __sincosf(Bp, &sB, &cB);
        size_t base = ((size_t)(hbase + hh) * 2048 + i) * 128 + d;
        Ub[base]      = f2bf(af * cA);
        Ub[base + 64] = f2bf(af * sA);
        Wb[base]      = f2bf(af * cB);
        Wb[base + 64] = f2bf(af * sB);
      }
    }
  }
}

// ------- single-pass MFMA flash, redundancy-free wave mapping ----------------
__global__ __launch_bounds__(512, 1) void k_flash6(const unsigned short* __restrict__ Ub,
    const unsigned short* __restrict__ Wb, const unsigned short* __restrict__ vT,
    unsigned short* __restrict__ attb) {
  __shared__ __align__(16) unsigned char s_w[2][128 * 272];  // [k][f 128 bf16 + pad]
  __shared__ __align__(16) unsigned char s_v[2][64 * 272];   // [d][k 128 bf16 + pad]
  __shared__ __align__(16) unsigned char s_p[2][64 * 272];   // [q][k 128 bf16 + pad]
  const int qt = blockIdx.x, h = blockIdx.y;
  const int q0 = qt * 64;
  const int t = threadIdx.x;
  const int wave = t >> 6, lane = t & 63;
  const int qg = wave & 3, dh = wave >> 2;
  const int m = lane & 15, quad = lane >> 4;
  const int sr = t >> 2, sp = t & 3;      // s_w staging: 128 rows x 4 parts
  const int vr = t >> 3, vp = t & 7;      // s_v staging: 64 rows x 8 parts
  short8 afr[4][4];
  #pragma unroll
  for (int g = 0; g < 4; ++g) {
    const unsigned short* urow = Ub + ((size_t)h * 2048 + q0 + g * 16 + m) * 128;
    #pragma unroll
    for (int fs = 0; fs < 4; ++fs)
      afr[g][fs] = *(const short8*)(urow + fs * 32 + quad * 8);
  }
  short8 ones;
  #pragma unroll
  for (int j = 0; j < 8; ++j) ones[j] = (short)0x3F80;   // bf16 1.0
  f32x4 oacc[2] = {{0,0,0,0},{0,0,0,0}};
  f32x4 dacc = {0, 0, 0, 0};
  const unsigned short* wgbase = Wb + (size_t)h * 2048 * 128 + (size_t)sr * 128;
  const unsigned short* vgbase = vT + ((size_t)h * 64 + vr) * 2048;
  #pragma unroll
  for (int it = 0; it < 4; ++it)
    *(short8*)(s_w[0] + sr * 272 + sp * 64 + it * 16) =
      *(const short8*)(wgbase + sp * 32 + it * 8);
  #pragma unroll
  for (int it = 0; it < 2; ++it)
    *(short8*)(s_v[0] + vr * 272 + vp * 32 + it * 16) =
      *(const short8*)(vgbase + vp * 16 + it * 8);
  __syncthreads();
  for (int kt = 0; kt < 16; ++kt) {
    const int cur = kt & 1;
    short8 wst[4], vst[2];
    const bool has = (kt < 15);
    if (has) {
      const unsigned short* wg = wgbase + (size_t)(kt + 1) * 128 * 128;
      #pragma unroll
      for (int it = 0; it < 4; ++it)
        wst[it] = *(const short8*)(wg + sp * 32 + it * 8);
      const unsigned short* vg = vgbase + (kt + 1) * 128;
      #pragma unroll
      for (int it = 0; it < 2; ++it)
        vst[it] = *(const short8*)(vg + vp * 16 + it * 8);
    }
    // scores: S[64q x 16k-strip] per wave; 4 B-frag reads, 16 MFMA
    f32x4 sc[4] = {{0,0,0,0},{0,0,0,0},{0,0,0,0},{0,0,0,0}};
    #pragma unroll
    for (int fs = 0; fs < 4; ++fs) {
      short8 bfr = *(const short8*)(s_w[cur] + (wave * 16 + m) * 272 + fs * 64 + quad * 16);
      #pragma unroll
      for (int g = 0; g < 4; ++g)
        sc[g] = MFMA16(afr[g][fs], bfr, sc[g]);
    }
    #pragma unroll
    for (int g = 0; g < 4; ++g)
      #pragma unroll
      for (int r = 0; r < 4; ++r) {
        float p = __expf(sc[g][r] * 0.125f);
        *(unsigned short*)(s_p[cur] + (g * 16 + quad * 4 + r) * 272 +
                           (wave * 16 + m) * 2) = f2bf(p);
      }
    short8 vf[4][2];
    #pragma unroll
    for (int k2 = 0; k2 < 4; ++k2)
      #pragma unroll
      for (int dt = 0; dt < 2; ++dt)
        vf[k2][dt] = *(const short8*)(s_v[cur] + (dh * 32 + dt * 16 + m) * 272 +
                                      k2 * 64 + quad * 16);
    if (has) {
      #pragma unroll
      for (int it = 0; it < 4; ++it)
        *(short8*)(s_w[cur ^ 1] + sr * 272 + sp * 64 + it * 16) = wst[it];
      #pragma unroll
      for (int it = 0; it < 2; ++it)
        *(short8*)(s_v[cur ^ 1] + vr * 272 + vp * 32 + it * 16) = vst[it];
    }
    __syncthreads();
    #pragma unroll
    for (int k2 = 0; k2 < 4; ++k2) {
      short8 pf = *(const short8*)(s_p[cur] + (qg * 16 + m) * 272 + k2 * 64 + quad * 16);
      dacc = MFMA16(pf, ones, dacc);
      #pragma unroll
      for (int dt = 0; dt < 2; ++dt)
        oacc[dt] = MFMA16(pf, vf[k2][dt], oacc[dt]);
    }
  }
  float invd[4];
  #pragma unroll
  for (int r = 0; r < 4; ++r) invd[r] = 1.0f / dacc[r];
  #pragma unroll
  for (int dt = 0; dt < 2; ++dt)
    #pragma unroll
    for (int r = 0; r < 4; ++r)
      attb[(size_t)(q0 + qg * 16 + quad * 4 + r) * 512 + h * 64 +
           dh * 32 + dt * 16 + m] = f2bf(oacc[dt][r] * invd[r]);
}

// ------- out GEMM: out f32 = attb @ WoT^T + bo ----------------
__global__ __launch_bounds__(256) void k_gemm(const unsigned short* __restrict__ A,
    const unsigned short* __restrict__ Bt, const float* __restrict__ bias,
    float* __restrict__ C, int N) {
  __shared__ __align__(16) unsigned char sm[2 * 64 * 136];
  unsigned char* s_a = sm;
  unsigned char* s_b = sm + 64 * 136;
  const int m0 = blockIdx.x * 64, n0 = blockIdx.y * 64;
  const int t = threadIdx.x;
  const int wave = t >> 6, lane = t & 63;
  const int m = lane & 15, quad = lane >> 4;
  const int sr = t >> 2, spart = t & 3;
  f32x4 acc[4] = {{0,0,0,0},{0,0,0,0},{0,0,0,0},{0,0,0,0}};
  for (int kc = 0; kc < 512; kc += 64) {
    #pragma unroll
    for (int it = 0; it < 2; ++it) {
      *(short8*)(s_a + sr * 136 + spart * 32 + it * 16) =
        *(const short8*)(A + (size_t)(m0 + sr) * 512 + kc + spart * 16 + it * 8);
      *(short8*)(s_b + sr * 136 + spart * 32 + it * 16) =
        *(const short8*)(Bt + (size_t)(n0 + sr) * 512 + kc + spart * 16 + it * 8);
    }
    __syncthreads();
    #pragma unroll
    for (int k2 = 0; k2 < 2; ++k2) {
      short8 af = *(const short8*)(s_a + (wave * 16 + m) * 136 + k2 * 64 + quad * 16);
      #pragma unroll
      for (int nt = 0; nt < 4; ++nt) {
        short8 bf = *(const short8*)(s_b + (nt * 16 + m) * 136 + k2 * 64 + quad * 16);
        acc[nt] = MFMA16(af, bf, acc[nt]);
      }
    }
    __syncthreads();
  }
  #pragma unroll
  for (int nt = 0; nt < 4; ++nt) {
    int col = n0 + nt * 16 + m;
    float bv = bias[col];
    #pragma unroll
    for (int r = 0; r < 4; ++r) {
      int row = m0 + wave * 16 + quad * 4 + r;
      C[(size_t)row * N + col] = acc[nt][r] + bv;
    }
  }
}

extern "C" void kernel_launch(void* const* d_in, const int* in_sizes, int n_in,
                              void* d_out, int out_size, void* d_ws, size_t ws_size,
                              hipStream_t stream) {
  (void)in_sizes; (void)n_in; (void)out_size; (void)ws_size;
  const float* x   = (const float*)d_in[0];
  const float* Wq  = (const float*)d_in[1];
  const float* bq  = (const float*)d_in[2];
  const float* lnw = (const float*)d_in[3];
  const float* lnb = (const float*)d_in[4];
  const float* fr  = (const float*)d_in[5];
  const float* ps  = (const float*)d_in[6];
  const float* Wo  = (const float*)d_in[7];
  const float* bo  = (const float*)d_in[8];
  // d_in[9] = cos_table: unused (smooth-cos factorization)
  char* ws = (char*)d_ws;
  unsigned short* attb = (unsigned short*)(ws + B_ATTB);
  unsigned short* Ub   = (unsigned short*)(ws + B_UB);
  unsigned short* Wb   = (unsigned short*)(ws + B_WB);
  unsigned short* vT   = (unsigned short*)(ws + B_VT);
  unsigned short* WqTp = (unsigned short*)(ws + B_WQT);
  unsigned short* WoT  = (unsigned short*)(ws + B_WOT);
  float* out = (float*)d_out;

  k_prep<<<448, 256, 0, stream>>>(x, Wq, Wo, vT, WqTp, WoT);
  k_qs_ln<<<128, 512, 0, stream>>>(x, WqTp, bq, lnw, lnb, fr, ps, Ub, Wb);
  k_flash6<<<dim3(32, 8), 512, 0, stream>>>(Ub, Wb, vT, attb);
  k_gemm<<<dim3(32, 8), 256, 0, stream>>>(attb, WoT, bo, out, 512);
}